// Round 6
// baseline (3281.338 us; speedup 1.0000x reference)
//
#include <hip/hip_runtime.h>

typedef _Float16 half_t;
typedef _Float16 half8  __attribute__((ext_vector_type(8)));
typedef float    f32x4  __attribute__((ext_vector_type(4)));
typedef int      i32x4  __attribute__((ext_vector_type(4)));

#define NB 64
#define NT 256
#define NI 1024
#define NH 512
#define MFMA16 __builtin_amdgcn_mfma_f32_16x16x32_f16

// ---- cache-bypassing (MALL-coherent) ops ----
__device__ __forceinline__ void gload16_cc(i32x4& v, const void* p) {
    asm volatile("global_load_dwordx4 %0, %1, off sc0 sc1"
                 : "=v"(v) : "v"(p) : "memory");
}
__device__ __forceinline__ void gstore16_cc(void* p, i32x4 v) {
    asm volatile("global_store_dwordx4 %0, %1, off sc0 sc1"
                 :: "v"(p), "v"(v) : "memory");
}
__device__ __forceinline__ unsigned gloadu16_cc(const void* p) {
    unsigned v;
    asm volatile("global_load_ushort %0, %1, off sc0 sc1"
                 : "=v"(v) : "v"(p) : "memory");
    return v;
}

// ---------------- flag-array group barrier (s_sleep restored) ----------------
__device__ __forceinline__ void flag_barrier(unsigned* slots, int nslots,
                                             int my, unsigned gen, int tid) {
    if (tid < 64) {
        asm volatile("s_waitcnt vmcnt(0)" ::: "memory");
        if (tid == 0) {
            unsigned gv = gen;
            asm volatile("global_store_dword %0, %1, off sc0 sc1"
                         :: "v"(slots + my), "v"(gv) : "memory");
        }
        const unsigned* p = slots + (tid & (nslots - 1));
        int guard = 0;
        while (true) {
            unsigned v;
            asm volatile("global_load_dword %0, %1, off sc0 sc1"
                         : "=v"(v) : "v"(p) : "memory");
            asm volatile("s_waitcnt vmcnt(0)" ::: "memory");
            if (__all(v >= gen)) break;
            __builtin_amdgcn_s_sleep(1);
            if (++guard > (1 << 22)) break;   // failsafe: wrong beats hang
        }
    }
    __syncthreads();
}

// ---------------- fp32 -> fp16 convert ----------------
__global__ __launch_bounds__(256) void k_cvt(const float* __restrict__ s,
                                             half_t* __restrict__ d, int n4) {
    int i = blockIdx.x * 256 + threadIdx.x;
    if (i < n4) {
        float4 v = reinterpret_cast<const float4*>(s)[i];
        half_t h4[4] = {(half_t)v.x, (half_t)v.y, (half_t)v.z, (half_t)v.w};
        *reinterpret_cast<long*>(&d[i * 4]) = *reinterpret_cast<long*>(h4);
    }
}

// ---------------- GEMM: C[M,N](f16) = A[M,K](fp32) * Bw[N,K]^T + bias ----------------
template <int K>
__global__ __launch_bounds__(256) void k_gemm(const float* __restrict__ Af,
                                              const half_t* __restrict__ Bw,
                                              const float* __restrict__ bias,
                                              half_t* __restrict__ C, int N, int ldc) {
    constexpr int BK = 64;
    __shared__ half_t Al[2][128 * BK] __attribute__((aligned(16)));
    __shared__ half_t Bl[2][128 * BK] __attribute__((aligned(16)));

    const int tid = threadIdx.x, lane = tid & 63, wv = tid >> 6;
    const long m0 = (long)blockIdx.y * 128;
    const long n0 = (long)blockIdx.x * 128;
    const int wm = (wv >> 1) * 64, wn = (wv & 1) * 64;

    f32x4 acc[4][4];
#pragma unroll
    for (int nt = 0; nt < 4; ++nt) {
        float bv = bias[n0 + wn + nt * 16 + (lane & 15)];
#pragma unroll
        for (int mt = 0; mt < 4; ++mt) acc[mt][nt] = (f32x4){bv, bv, bv, bv};
    }

    auto stage = [&](int buf, int kt) {
#pragma unroll
        for (int j = 0; j < 4; ++j) {
            int c = tid + 256 * j;
            int row = c >> 3, cin = c & 7;
            int dst = row * BK + ((cin ^ (row & 7)) << 3);
            const float* src = Af + (m0 + row) * K + kt * BK + cin * 8;
            float4 f0 = *reinterpret_cast<const float4*>(src);
            float4 f1 = *reinterpret_cast<const float4*>(src + 4);
            half8 h;
            h[0] = (half_t)f0.x; h[1] = (half_t)f0.y; h[2] = (half_t)f0.z; h[3] = (half_t)f0.w;
            h[4] = (half_t)f1.x; h[5] = (half_t)f1.y; h[6] = (half_t)f1.z; h[7] = (half_t)f1.w;
            *reinterpret_cast<half8*>(&Al[buf][dst]) = h;
            *reinterpret_cast<int4*>(&Bl[buf][dst]) =
                *reinterpret_cast<const int4*>(Bw + (n0 + row) * K + kt * BK + cin * 8);
        }
    };

    stage(0, 0);
    __syncthreads();
    constexpr int NK = K / BK;
    int buf = 0;
    for (int kt = 0; kt < NK; ++kt) {
        if (kt + 1 < NK) stage(buf ^ 1, kt + 1);
        half8 af[4][2], bf[4][2];
#pragma unroll
        for (int mt = 0; mt < 4; ++mt)
#pragma unroll
            for (int ks = 0; ks < 2; ++ks) {
                int lr = wm + mt * 16 + (lane & 15);
                int off = lr * BK + ((ks * 32 + 8 * (lane >> 4)) ^ ((lr & 7) << 3));
                af[mt][ks] = *reinterpret_cast<const half8*>(&Al[buf][off]);
            }
#pragma unroll
        for (int nt = 0; nt < 4; ++nt)
#pragma unroll
            for (int ks = 0; ks < 2; ++ks) {
                int lr = wn + nt * 16 + (lane & 15);
                int off = lr * BK + ((ks * 32 + 8 * (lane >> 4)) ^ ((lr & 7) << 3));
                bf[nt][ks] = *reinterpret_cast<const half8*>(&Bl[buf][off]);
            }
#pragma unroll
        for (int mt = 0; mt < 4; ++mt)
#pragma unroll
            for (int nt = 0; nt < 4; ++nt)
#pragma unroll
                for (int ks = 0; ks < 2; ++ks)
                    acc[mt][nt] = MFMA16(af[mt][ks], bf[nt][ks], acc[mt][nt], 0, 0, 0);
        __syncthreads();
        buf ^= 1;
    }
#pragma unroll
    for (int mt = 0; mt < 4; ++mt)
#pragma unroll
        for (int nt = 0; nt < 4; ++nt)
#pragma unroll
            for (int i = 0; i < 4; ++i) {
                long row = m0 + wm + mt * 16 + 4 * (lane >> 4) + i;
                long col = n0 + wn + nt * 16 + (lane & 15);
                C[row * (long)ldc + col] = (half_t)acc[mt][nt][i];
            }
}

// ---------------- Fused persistent kernel: both recurrences overlapped -------
// bid < 64  : PHASE1 role — 1 group x 64 WGs, all 64 batches, 8 h-elems/WG.
//             Wave 3 computes gx2(t-1) rows [memb*48,+48) from the LDS h-tile.
//             flag slots1[memb] = t+2  <=>  h1(t) and gx2(t-1) visible.
// bid 64-191: PHASE2 role — 2 groups x 64 WGs, 32 batches, 16 out-elems/WG.
//             Step s needs own flags >= s+1 and slots1 >= s+3 (gx2(s) ready).
__global__ __launch_bounds__(256, 1) void k_fused(
    const half_t* __restrict__ whh1, const float* __restrict__ bhh1,
    const half_t* __restrict__ wih2, const float* __restrict__ bih2,
    const half_t* __restrict__ whh2, const float* __restrict__ bhh2,
    half_t* gxU, float* __restrict__ out,
    half_t* h1buf, half_t* h2buf,
    unsigned* slots1, unsigned* slots2) {

    __shared__ __attribute__((aligned(16))) char arena[160768];
    const int tid = threadIdx.x, lane = tid & 63, wv = tid >> 6;
    const int bid = blockIdx.x;

    if (bid < 64) {
        // ======================= PHASE 1 =======================
        half_t* wl   = (half_t*)arena;                 // 32 x 512 (rz 0-15, n 16-23, zero 24-31)
        half_t* wl2  = (half_t*)(arena + 32768);       // 48 x 512 wih2 slice
        half_t* hl   = (half_t*)(arena + 81920);       // 64 x 512 h-tile
        float*  xch  = (float* )(arena + 147456);      // [3][64][8]
        half_t* gxst = (half_t*)(arena + 153600);      // [64][48]
        half_t* hst  = (half_t*)(arena + 159744);      // [64][8]
        const int memb = bid, e0 = memb * 8;

        // stage whh1 (rz packed + n + zero pad)
#pragma unroll
        for (int j = 0; j < 8; ++j) {
            int c = tid + 256 * j, lr = c >> 6, cin = c & 63;
            i32x4 v = (i32x4){0, 0, 0, 0};
            if (lr < 24)
                v = *(const i32x4*)(whh1 + (long)((lr >> 3) * NH + e0 + (lr & 7)) * NH + cin * 8);
            *(i32x4*)&wl[lr * NH + ((cin ^ (lr & 7)) << 3)] = v;
        }
        // stage wih2 rows [memb*48, +48)
#pragma unroll
        for (int j = 0; j < 12; ++j) {
            int c = tid + 256 * j, lr = c >> 6, cin = c & 63;
            *(i32x4*)&wl2[lr * NH + ((cin ^ (lr & 7)) << 3)] =
                *(const i32x4*)(wih2 + (long)(memb * 48 + lr) * NH + cin * 8);
        }
        // zero h1 buf0 slice (batch tid, elems e0..e0+8)
        if (tid < 64) {
            i32x4 z = (i32x4){0, 0, 0, 0};
            gstore16_cc(h1buf + tid * NH + e0, z);
        }
        __syncthreads();
        flag_barrier(slots1, 64, memb, 1, tid);

        const int e = tid & 7, b0 = tid >> 3, b1 = b0 + 32;
        const float bh_r = bhh1[e0 + e], bh_z = bhh1[NH + e0 + e], bh_n = bhh1[2 * NH + e0 + e];
        float bi2[3] = {0.f, 0.f, 0.f};
        if (wv == 3) {
#pragma unroll
            for (int nt = 0; nt < 3; ++nt)
                bi2[nt] = bih2[memb * 48 + nt * 16 + (lane & 15)];
        }
        float hp0 = 0.f, hp1 = 0.f;
        const int cin = tid & 63, r0 = tid >> 6;

        auto load_h = [&](int buf) {
            i32x4 sv[16];
            const half_t* hsrc = h1buf + buf * (NB * NH);
#pragma unroll
            for (int j = 0; j < 16; ++j)
                gload16_cc(sv[j], hsrc + (r0 + 4 * j) * NH + cin * 8);
            asm volatile("s_waitcnt vmcnt(0)" ::: "memory");
            __builtin_amdgcn_sched_barrier(0);
#pragma unroll
            for (int j = 0; j < 16; ++j) {
                int lr = r0 + 4 * j;
                *(i32x4*)&hl[lr * NH + ((cin ^ (lr & 7)) << 3)] = sv[j];
            }
        };

        auto wave3_gx2 = [&]() {   // gx2 for the h currently in hl -> gxst (+bias, relu'd)
            f32x4 g2[4][3];
#pragma unroll
            for (int mt = 0; mt < 4; ++mt)
#pragma unroll
                for (int nt = 0; nt < 3; ++nt) g2[mt][nt] = (f32x4){0.f, 0.f, 0.f, 0.f};
#pragma unroll
            for (int ks = 0; ks < 16; ++ks) {
                int ko = ks * 32 + 8 * (lane >> 4);
                half8 a[4];
#pragma unroll
                for (int mt = 0; mt < 4; ++mt) {
                    int ar = mt * 16 + (lane & 15);
                    a[mt] = *(const half8*)&hl[ar * NH + (ko ^ ((ar & 7) << 3))];
#pragma unroll
                    for (int jj = 0; jj < 8; ++jj)
                        a[mt][jj] = a[mt][jj] > (half_t)0.f ? a[mt][jj] : (half_t)0.f;
                }
#pragma unroll
                for (int nt = 0; nt < 3; ++nt) {
                    int br = nt * 16 + (lane & 15);
                    half8 bf = *(const half8*)&wl2[br * NH + (ko ^ ((br & 7) << 3))];
#pragma unroll
                    for (int mt = 0; mt < 4; ++mt)
                        g2[mt][nt] = MFMA16(a[mt], bf, g2[mt][nt], 0, 0, 0);
                }
            }
            int col = lane & 15, brow4 = 4 * (lane >> 4);
#pragma unroll
            for (int mt = 0; mt < 4; ++mt)
#pragma unroll
                for (int nt = 0; nt < 3; ++nt)
#pragma unroll
                    for (int i = 0; i < 4; ++i)
                        gxst[(mt * 16 + brow4 + i) * 48 + nt * 16 + col] =
                            (half_t)(g2[mt][nt][i] + bi2[nt]);
        };

        auto gx2_store = [&](int trow) {   // tid<64 only: 6 chunks each, covered by wave0 vmcnt
#pragma unroll
            for (int rr = 0; rr < 6; ++rr) {
                int c = tid + 64 * rr;         // 0..383
                int bb = c / 6, kk = c - bb * 6;
                gstore16_cc(gxU + ((long)bb * NT + trow) * 3072 + memb * 48 + kk * 8,
                            *(i32x4*)&gxst[bb * 48 + kk * 8]);
            }
        };

        for (int t = 0; t < NT; ++t) {
            // gx1(t) (plain loads; gemm1 output) — issued alongside h loads
            long g0 = ((long)b0 * NT + t) * 3072 + e0 + e;
            long g1 = ((long)b1 * NT + t) * 3072 + e0 + e;
            float xr0 = (float)gxU[g0], xz0 = (float)gxU[g0 + NH], xn0 = (float)gxU[g0 + 2 * NH];
            float xr1 = (float)gxU[g1], xz1 = (float)gxU[g1 + NH], xn1 = (float)gxU[g1 + 2 * NH];
            load_h(t & 1);
            __syncthreads();

            if (wv < 2) {                       // rz-packed tile, M-tiles wv*2, wv*2+1
#pragma unroll
                for (int mt2 = 0; mt2 < 2; ++mt2) {
                    const int mt = wv * 2 + mt2;
                    f32x4 a0 = (f32x4){0, 0, 0, 0}, a1 = (f32x4){0, 0, 0, 0};
#pragma unroll
                    for (int ks = 0; ks < 16; ks += 2) {
                        int ar = mt * 16 + (lane & 15);
                        int br = lane & 15;
                        int ko0 = ks * 32 + 8 * (lane >> 4), ko1 = ko0 + 32;
                        a0 = MFMA16(*(const half8*)&hl[ar * NH + (ko0 ^ ((ar & 7) << 3))],
                                    *(const half8*)&wl[br * NH + (ko0 ^ ((br & 7) << 3))], a0, 0, 0, 0);
                        a1 = MFMA16(*(const half8*)&hl[ar * NH + (ko1 ^ ((ar & 7) << 3))],
                                    *(const half8*)&wl[br * NH + (ko1 ^ ((br & 7) << 3))], a1, 0, 0, 0);
                    }
                    f32x4 acc = a0 + a1;
                    int col = lane & 15, brow = mt * 16 + 4 * (lane >> 4);
#pragma unroll
                    for (int i = 0; i < 4; ++i) {
                        if (col < 8) xch[(brow + i) * 8 + col] = acc[i];
                        else         xch[512 + (brow + i) * 8 + (col - 8)] = acc[i];
                    }
                }
            } else if (wv == 2) {               // n tile, M-tiles 0..3
#pragma unroll
                for (int mt = 0; mt < 4; ++mt) {
                    f32x4 a0 = (f32x4){0, 0, 0, 0}, a1 = (f32x4){0, 0, 0, 0};
#pragma unroll
                    for (int ks = 0; ks < 16; ks += 2) {
                        int ar = mt * 16 + (lane & 15);
                        int br = 16 + (lane & 15);
                        int ko0 = ks * 32 + 8 * (lane >> 4), ko1 = ko0 + 32;
                        a0 = MFMA16(*(const half8*)&hl[ar * NH + (ko0 ^ ((ar & 7) << 3))],
                                    *(const half8*)&wl[br * NH + (ko0 ^ ((br & 7) << 3))], a0, 0, 0, 0);
                        a1 = MFMA16(*(const half8*)&hl[ar * NH + (ko1 ^ ((ar & 7) << 3))],
                                    *(const half8*)&wl[br * NH + (ko1 ^ ((br & 7) << 3))], a1, 0, 0, 0);
                    }
                    f32x4 acc = a0 + a1;
                    int col = lane & 15, brow = mt * 16 + 4 * (lane >> 4);
                    if (col < 8) {
#pragma unroll
                        for (int i = 0; i < 4; ++i)
                            xch[1024 + (brow + i) * 8 + col] = acc[i];
                    }
                }
            } else {                            // wave 3: gx2(t-1)
                if (t > 0) wave3_gx2();
            }
            __syncthreads();

            {   // combine, 2 items per thread
                float dr = xch[b0 * 8 + e], dz = xch[512 + b0 * 8 + e], dn = xch[1024 + b0 * 8 + e];
                float r = 1.f / (1.f + __expf(-(xr0 + dr + bh_r)));
                float z = 1.f / (1.f + __expf(-(xz0 + dz + bh_z)));
                float n = tanhf(xn0 + r * (dn + bh_n));
                hp0 = (1.f - z) * n + z * hp0;
                hst[b0 * 8 + e] = (half_t)hp0;
            }
            {
                float dr = xch[b1 * 8 + e], dz = xch[512 + b1 * 8 + e], dn = xch[1024 + b1 * 8 + e];
                float r = 1.f / (1.f + __expf(-(xr1 + dr + bh_r)));
                float z = 1.f / (1.f + __expf(-(xz1 + dz + bh_z)));
                float n = tanhf(xn1 + r * (dn + bh_n));
                hp1 = (1.f - z) * n + z * hp1;
                hst[b1 * 8 + e] = (half_t)hp1;
            }
            __syncthreads();

            if (tid < 64) {                     // all flagged stores from wave 0
                gstore16_cc(h1buf + ((t + 1) & 1) * (NB * NH) + tid * NH + e0,
                            *(i32x4*)&hst[tid * 8]);
                if (t > 0) gx2_store(t - 1);
            }
            flag_barrier(slots1, 64, memb, t + 2, tid);
        }
        // epilogue: gx2(NT-1)
        load_h(NT & 1);
        __syncthreads();
        if (wv == 3) wave3_gx2();
        __syncthreads();
        if (tid < 64) {
            gx2_store(NT - 1);
            asm volatile("s_waitcnt vmcnt(0)" ::: "memory");
            if (tid == 0) {
                unsigned gv = NT + 2;
                asm volatile("global_store_dword %0, %1, off sc0 sc1"
                             :: "v"(slots1 + memb), "v"(gv) : "memory");
            }
        }
    } else {
        // ======================= PHASE 2 =======================
        half_t* wl2h = (half_t*)arena;                 // 48 x 1024
        half_t* hl2  = (half_t*)(arena + 98304);       // 32 x 512 (one K-half)
        float*  xch2 = (float* )(arena + 131072);      // [3][32][16]
        half_t* hst  = (half_t*)(arena + 137216);      // [32][16]
        const int q = (bid - 64) >> 6, memb = (bid - 64) & 63;
        const int e0 = memb * 16;
        unsigned* myslots = slots2 + q * 64;

#pragma unroll
        for (int j = 0; j < 24; ++j) {
            int c = tid + 256 * j, lr = c >> 7, cin = c & 127;
            *(i32x4*)&wl2h[lr * NI + ((cin ^ (lr & 7)) << 3)] =
                *(const i32x4*)(whh2 + (long)((lr >> 4) * NI + e0 + (lr & 15)) * NI + cin * 8);
        }
        if (tid < 64) {
            i32x4 z = (i32x4){0, 0, 0, 0};
            gstore16_cc(h2buf + (q * 32 + (tid >> 1)) * NI + e0 + (tid & 1) * 8, z);
        }
        __syncthreads();
        flag_barrier(myslots, 64, memb, 1, tid);
        // wait for producer generation 3 (gx2(0) visible)
        if (tid < 64) {
            int guard = 0;
            while (true) {
                unsigned v;
                asm volatile("global_load_dword %0, %1, off sc0 sc1"
                             : "=v"(v) : "v"(slots1 + lane) : "memory");
                asm volatile("s_waitcnt vmcnt(0)" ::: "memory");
                if (__all(v >= 3u)) break;
                __builtin_amdgcn_s_sleep(1);
                if (++guard > (1 << 22)) break;
            }
        }
        __syncthreads();

        const int e = tid & 15, bl0 = tid >> 4, bl1 = bl0 + 16;
        const long gb0 = (long)(q * 32 + bl0), gb1 = (long)(q * 32 + bl1);
        const float bh_r = bhh2[e0 + e], bh_z = bhh2[NI + e0 + e], bh_n = bhh2[2 * NI + e0 + e];
        float hp0 = 0.f, hp1 = 0.f;
        const int cin = tid & 127, khalf = cin >> 6, cinl = cin & 63, r0 = tid >> 7;

        for (int s = 0; s < NT; ++s) {
            if (s > 0) {                        // deferred out stores (drain with h loads)
                out[(gb0 * NT + (s - 1)) * NI + e0 + e] = hp0;
                out[(gb1 * NT + (s - 1)) * NI + e0 + e] = hp1;
            }
            i32x4 sv[16];
            const half_t* hsrc = h2buf + (s & 1) * (NB * NI);
#pragma unroll
            for (int j = 0; j < 16; ++j)
                gload16_cc(sv[j], hsrc + (q * 32 + r0 + 2 * j) * NI + cin * 8);
            unsigned ur0 = gloadu16_cc(gxU + (gb0 * NT + s) * 3072 + e0 + e);
            unsigned uz0 = gloadu16_cc(gxU + (gb0 * NT + s) * 3072 + NI + e0 + e);
            unsigned un0 = gloadu16_cc(gxU + (gb0 * NT + s) * 3072 + 2 * NI + e0 + e);
            unsigned ur1 = gloadu16_cc(gxU + (gb1 * NT + s) * 3072 + e0 + e);
            unsigned uz1 = gloadu16_cc(gxU + (gb1 * NT + s) * 3072 + NI + e0 + e);
            unsigned un1 = gloadu16_cc(gxU + (gb1 * NT + s) * 3072 + 2 * NI + e0 + e);
            asm volatile("s_waitcnt vmcnt(0)" ::: "memory");
            __builtin_amdgcn_sched_barrier(0);
            float xr0 = (float)*(half_t*)&ur0, xz0 = (float)*(half_t*)&uz0, xn0 = (float)*(half_t*)&un0;
            float xr1 = (float)*(half_t*)&ur1, xz1 = (float)*(half_t*)&uz1, xn1 = (float)*(half_t*)&un1;

            f32x4 p0[2] = {(f32x4){0, 0, 0, 0}, (f32x4){0, 0, 0, 0}};
            f32x4 p1[2] = {(f32x4){0, 0, 0, 0}, (f32x4){0, 0, 0, 0}};
#pragma unroll
            for (int kh = 0; kh < 2; ++kh) {
                if (khalf == kh) {              // stage this K-half
#pragma unroll
                    for (int j = 0; j < 16; ++j) {
                        int lr = r0 + 2 * j;
                        *(i32x4*)&hl2[lr * NH + ((cinl ^ (lr & 7)) << 3)] = sv[j];
                    }
                }
                __syncthreads();
                if (wv < 3) {
#pragma unroll
                    for (int mt = 0; mt < 2; ++mt) {
                        f32x4 a0 = p0[mt], a1 = p1[mt];
#pragma unroll
                        for (int ks = 0; ks < 16; ks += 2) {
                            int ar = mt * 16 + (lane & 15);
                            int br = wv * 16 + (lane & 15);
                            int ko0 = ks * 32 + 8 * (lane >> 4), ko1 = ko0 + 32;
                            int bk0 = kh * 512 + ko0, bk1 = kh * 512 + ko1;
                            a0 = MFMA16(*(const half8*)&hl2[ar * NH + (ko0 ^ ((ar & 7) << 3))],
                                        *(const half8*)&wl2h[br * NI + (bk0 ^ ((br & 7) << 3))], a0, 0, 0, 0);
                            a1 = MFMA16(*(const half8*)&hl2[ar * NH + (ko1 ^ ((ar & 7) << 3))],
                                        *(const half8*)&wl2h[br * NI + (bk1 ^ ((br & 7) << 3))], a1, 0, 0, 0);
                        }
                        p0[mt] = a0; p1[mt] = a1;
                    }
                }
                __syncthreads();
            }
            if (wv < 3) {
#pragma unroll
                for (int mt = 0; mt < 2; ++mt) {
                    f32x4 acc = p0[mt] + p1[mt];
#pragma unroll
                    for (int i = 0; i < 4; ++i)
                        xch2[wv * 512 + (mt * 16 + 4 * (lane >> 4) + i) * 16 + (lane & 15)] = acc[i];
                }
            }
            __syncthreads();

            {
                float dr = xch2[bl0 * 16 + e], dz = xch2[512 + bl0 * 16 + e], dn = xch2[1024 + bl0 * 16 + e];
                float r = 1.f / (1.f + __expf(-(xr0 + dr + bh_r)));
                float z = 1.f / (1.f + __expf(-(xz0 + dz + bh_z)));
                float n = tanhf(xn0 + r * (dn + bh_n));
                hp0 = (1.f - z) * n + z * hp0;
                hst[bl0 * 16 + e] = (half_t)hp0;
            }
            {
                float dr = xch2[bl1 * 16 + e], dz = xch2[512 + bl1 * 16 + e], dn = xch2[1024 + bl1 * 16 + e];
                float r = 1.f / (1.f + __expf(-(xr1 + dr + bh_r)));
                float z = 1.f / (1.f + __expf(-(xz1 + dz + bh_z)));
                float n = tanhf(xn1 + r * (dn + bh_n));
                hp1 = (1.f - z) * n + z * hp1;
                hst[bl1 * 16 + e] = (half_t)hp1;
            }
            __syncthreads();

            if (s + 1 < NT) {
                if (tid < 64)
                    gstore16_cc(h2buf + ((s + 1) & 1) * (NB * NI) + (q * 32 + (tid >> 1)) * NI + e0 + (tid & 1) * 8,
                                *(i32x4*)&hst[(tid >> 1) * 16 + (tid & 1) * 8]);
                if (tid < 64) {                 // dual-poll barrier: own s+2, producer s+4
                    asm volatile("s_waitcnt vmcnt(0)" ::: "memory");
                    if (tid == 0) {
                        unsigned gv = s + 2;
                        asm volatile("global_store_dword %0, %1, off sc0 sc1"
                                     :: "v"(myslots + memb), "v"(gv) : "memory");
                    }
                    int guard = 0;
                    while (true) {
                        unsigned v1, v2;
                        asm volatile("global_load_dword %0, %1, off sc0 sc1"
                                     : "=v"(v1) : "v"(myslots + lane) : "memory");
                        asm volatile("global_load_dword %0, %1, off sc0 sc1"
                                     : "=v"(v2) : "v"(slots1 + lane) : "memory");
                        asm volatile("s_waitcnt vmcnt(0)" ::: "memory");
                        if (__all((v1 >= (unsigned)(s + 2)) && (v2 >= (unsigned)(s + 4)))) break;
                        __builtin_amdgcn_s_sleep(1);
                        if (++guard > (1 << 22)) break;
                    }
                }
                __syncthreads();
            }
        }
        out[(gb0 * NT + (NT - 1)) * NI + e0 + e] = hp0;
        out[(gb1 * NT + (NT - 1)) * NI + e0 + e] = hp1;
    }
}

// ---------------- launcher ----------------
extern "C" void kernel_launch(void* const* d_in, const int* in_sizes, int n_in,
                              void* d_out, int out_size, void* d_ws, size_t ws_size,
                              hipStream_t stream) {
    const float* x     = (const float*)d_in[0];
    const float* w_ih1 = (const float*)d_in[1];
    const float* w_hh1 = (const float*)d_in[2];
    const float* b_ih1 = (const float*)d_in[3];
    const float* b_hh1 = (const float*)d_in[4];
    const float* w_ih2 = (const float*)d_in[5];
    const float* w_hh2 = (const float*)d_in[6];
    const float* b_ih2 = (const float*)d_in[7];
    const float* b_hh2 = (const float*)d_in[8];

    char* ws = (char*)d_ws;
    // layout (ends 112MB; >=144MB proven usable):
    unsigned* slots1 = (unsigned*)ws;                  // [0, 256): phase1 flags
    unsigned* slots2 = (unsigned*)(ws + 1024);         // [1K, 1.5K): phase2 2x64 flags
    half_t* h1buf  = (half_t*)(ws + 4096);             // 2 x 64x512 fp16
    half_t* h2buf  = (half_t*)(ws + 135168);           // 2 x 64x1024 fp16
    half_t* wih1h  = (half_t*)(ws + 1048576);          // 1536x1024
    half_t* whh1h  = (half_t*)(ws + 4194304);          // 1536x512
    half_t* wih2h  = (half_t*)(ws + 5767168);          // 3072x512
    half_t* whh2h  = (half_t*)(ws + 8912896);          // 3072x1024 -> ends 14.9MB
    half_t* gxU    = (half_t*)(ws + 16777216);         // [16,112)MB: [B][T][3072]
    float*  out    = (float*)d_out;

    hipMemsetAsync(ws, 0, 4096, stream);               // all flags = 0

    k_cvt<<<1536, 256, 0, stream>>>(w_ih1, wih1h, 393216);
    k_cvt<<<768,  256, 0, stream>>>(w_hh1, whh1h, 196608);
    k_cvt<<<1536, 256, 0, stream>>>(w_ih2, wih2h, 393216);
    k_cvt<<<3072, 256, 0, stream>>>(w_hh2, whh2h, 786432);

    // gx1 = x @ w_ih1^T + b_ih1 into gxU cols [0,1536), row stride 3072
    k_gemm<1024><<<dim3(12, 128), 256, 0, stream>>>(x, wih1h, b_ih1, gxU, 1536, 3072);
    // overlapped recurrences (phase1: 64 WGs, phase2: 128 WGs)
    k_fused<<<192, 256, 0, stream>>>(whh1h, b_hh1, wih2h, b_ih2, whh2h, b_hh2,
                                     gxU, out, h1buf, h2buf, slots1, slots2);
}

// Round 7
// 2422.480 us; speedup vs baseline: 1.3545x; 1.3545x over previous
//
#include <hip/hip_runtime.h>

typedef _Float16 half_t;
typedef _Float16 half8  __attribute__((ext_vector_type(8)));
typedef float    f32x4  __attribute__((ext_vector_type(4)));
typedef int      i32x4  __attribute__((ext_vector_type(4)));

#define NB 64
#define NT 256
#define NI 1024
#define NH 512
#define MFMA16 __builtin_amdgcn_mfma_f32_16x16x32_f16

// ---- cache-bypassing (MALL-coherent) 16B load/store ----
__device__ __forceinline__ void gload16_cc(i32x4& v, const void* p) {
    asm volatile("global_load_dwordx4 %0, %1, off sc0 sc1"
                 : "=v"(v) : "v"(p) : "memory");
}
__device__ __forceinline__ void gstore16_cc(void* p, i32x4 v) {
    asm volatile("global_store_dwordx4 %0, %1, off sc0 sc1"
                 :: "v"(p), "v"(v) : "memory");
}

// ---------------- flag-array group barrier ----------------
// slots[i] = generation WG i has arrived at (monotone). Wave 0 drains its own
// global stores, leader stores its slot, all lanes poll all slots wave-wide.
// s_sleep(1) backoff is LOAD-BEARING (R5: removing it cost +275us on phase2 —
// continuous polling delays the flag/data propagation it waits on).
__device__ __forceinline__ void flag_barrier(unsigned* slots, int nslots,
                                             int my, unsigned gen, int tid) {
    if (tid < 64) {
        asm volatile("s_waitcnt vmcnt(0)" ::: "memory");   // h stores visible first
        if (tid == 0) {
            unsigned gv = gen;
            asm volatile("global_store_dword %0, %1, off sc0 sc1"
                         :: "v"(slots + my), "v"(gv) : "memory");
        }
        const unsigned* p = slots + (tid & (nslots - 1));
        int guard = 0;
        while (true) {
            unsigned v;
            asm volatile("global_load_dword %0, %1, off sc0 sc1"
                         : "=v"(v) : "v"(p) : "memory");
            asm volatile("s_waitcnt vmcnt(0)" ::: "memory");
            if (__all(v >= gen)) break;
            __builtin_amdgcn_s_sleep(1);
            if (++guard > (1 << 22)) break;   // failsafe: wrong beats hang
        }
    }
    __syncthreads();
}

// ---------------- fp32 -> fp16 convert ----------------
__global__ __launch_bounds__(256) void k_cvt(const float* __restrict__ s,
                                             half_t* __restrict__ d, int n4) {
    int i = blockIdx.x * 256 + threadIdx.x;
    if (i < n4) {
        float4 v = reinterpret_cast<const float4*>(s)[i];
        half_t h4[4] = {(half_t)v.x, (half_t)v.y, (half_t)v.z, (half_t)v.w};
        *reinterpret_cast<long*>(&d[i * 4]) = *reinterpret_cast<long*>(h4);
    }
}

// ---------------- GEMM: C[M,N](f16) = A[M,K] * Bw[N,K]^T + bias ----------------
// AF32/BF32: operand is fp32, converted to fp16 during LDS staging.
template <int K, bool AF32, bool BF32>
__global__ __launch_bounds__(256) void k_gemm(const void* __restrict__ Av,
                                              const void* __restrict__ Bv,
                                              const float* __restrict__ bias,
                                              half_t* __restrict__ C, int N, int ldc) {
    constexpr int BK = 64;
    __shared__ half_t Al[2][128 * BK] __attribute__((aligned(16)));
    __shared__ half_t Bl[2][128 * BK] __attribute__((aligned(16)));

    const int tid = threadIdx.x, lane = tid & 63, wv = tid >> 6;
    const long m0 = (long)blockIdx.y * 128;
    const long n0 = (long)blockIdx.x * 128;
    const int wm = (wv >> 1) * 64, wn = (wv & 1) * 64;

    f32x4 acc[4][4];
#pragma unroll
    for (int nt = 0; nt < 4; ++nt) {
        float bv = bias[n0 + wn + nt * 16 + (lane & 15)];
#pragma unroll
        for (int mt = 0; mt < 4; ++mt) acc[mt][nt] = (f32x4){bv, bv, bv, bv};
    }

    auto cvt8 = [](const float* src) {
        float4 f0 = *reinterpret_cast<const float4*>(src);
        float4 f1 = *reinterpret_cast<const float4*>(src + 4);
        half8 h;
        h[0] = (half_t)f0.x; h[1] = (half_t)f0.y; h[2] = (half_t)f0.z; h[3] = (half_t)f0.w;
        h[4] = (half_t)f1.x; h[5] = (half_t)f1.y; h[6] = (half_t)f1.z; h[7] = (half_t)f1.w;
        return h;
    };

    auto stage = [&](int buf, int kt) {
#pragma unroll
        for (int j = 0; j < 4; ++j) {
            int c = tid + 256 * j;
            int row = c >> 3, cin = c & 7;
            int dst = row * BK + ((cin ^ (row & 7)) << 3);
            if constexpr (AF32) {
                *reinterpret_cast<half8*>(&Al[buf][dst]) =
                    cvt8((const float*)Av + (m0 + row) * K + kt * BK + cin * 8);
            } else {
                *reinterpret_cast<int4*>(&Al[buf][dst]) =
                    *reinterpret_cast<const int4*>((const half_t*)Av + (m0 + row) * K + kt * BK + cin * 8);
            }
            if constexpr (BF32) {
                *reinterpret_cast<half8*>(&Bl[buf][dst]) =
                    cvt8((const float*)Bv + (n0 + row) * K + kt * BK + cin * 8);
            } else {
                *reinterpret_cast<int4*>(&Bl[buf][dst]) =
                    *reinterpret_cast<const int4*>((const half_t*)Bv + (n0 + row) * K + kt * BK + cin * 8);
            }
        }
    };

    stage(0, 0);
    __syncthreads();
    constexpr int NK = K / BK;
    int buf = 0;
    for (int kt = 0; kt < NK; ++kt) {
        if (kt + 1 < NK) stage(buf ^ 1, kt + 1);
        half8 af[4][2], bf[4][2];
#pragma unroll
        for (int mt = 0; mt < 4; ++mt)
#pragma unroll
            for (int ks = 0; ks < 2; ++ks) {
                int lr = wm + mt * 16 + (lane & 15);
                int off = lr * BK + ((ks * 32 + 8 * (lane >> 4)) ^ ((lr & 7) << 3));
                af[mt][ks] = *reinterpret_cast<const half8*>(&Al[buf][off]);
            }
#pragma unroll
        for (int nt = 0; nt < 4; ++nt)
#pragma unroll
            for (int ks = 0; ks < 2; ++ks) {
                int lr = wn + nt * 16 + (lane & 15);
                int off = lr * BK + ((ks * 32 + 8 * (lane >> 4)) ^ ((lr & 7) << 3));
                bf[nt][ks] = *reinterpret_cast<const half8*>(&Bl[buf][off]);
            }
#pragma unroll
        for (int mt = 0; mt < 4; ++mt)
#pragma unroll
            for (int nt = 0; nt < 4; ++nt)
#pragma unroll
                for (int ks = 0; ks < 2; ++ks)
                    acc[mt][nt] = MFMA16(af[mt][ks], bf[nt][ks], acc[mt][nt], 0, 0, 0);
        __syncthreads();
        buf ^= 1;
    }
#pragma unroll
    for (int mt = 0; mt < 4; ++mt)
#pragma unroll
        for (int nt = 0; nt < 4; ++nt)
#pragma unroll
            for (int i = 0; i < 4; ++i) {
                long row = m0 + wm + mt * 16 + 4 * (lane >> 4) + i;
                long col = n0 + wn + nt * 16 + (lane & 15);
                C[row * (long)ldc + col] = (half_t)acc[mt][nt][i];
            }
}

// ---------------- Phase 1: layer-1 recurrence (persistent) ----------------
// 8 groups x 32 WGs; group g owns batches [8g,8g+8). WG owns 16 h-elems.
// hrelu store for step t-1 deferred to the top of step t: drains in the h-load
// vmcnt(0), off the flag critical path.
__global__ __launch_bounds__(256, 1) void k_phase1(const half_t* __restrict__ whh,
                                                   const float* __restrict__ bhh,
                                                   const half_t* __restrict__ gx,
                                                   half_t* __restrict__ hrelu,
                                                   half_t* __restrict__ hf16,
                                                   unsigned* __restrict__ slots) {
    __shared__ half_t wl[48 * NH] __attribute__((aligned(16)));   // 48KB
    __shared__ half_t hl[16 * NH] __attribute__((aligned(16)));   // 16KB
    __shared__ float xch[3][8][16];
    __shared__ half_t hst[8][16] __attribute__((aligned(16)));

    const int tid = threadIdx.x, lane = tid & 63, wv = tid >> 6;
    const int g = blockIdx.x & 7, memb = blockIdx.x >> 3;
    const int e0 = memb * 16;
    unsigned* gslots = slots + g * 64;

    // gate weights: local row lr = 16*gate + e -> global row gate*512 + e0 + e
#pragma unroll
    for (int j = 0; j < 12; ++j) {
        int c = tid + 256 * j;                 // 3072 chunks
        int lr = c >> 6, cin = c & 63;
        int grow = (lr >> 4) * NH + e0 + (lr & 15);
        int dst = lr * NH + ((cin ^ (lr & 7)) << 3);
        *reinterpret_cast<int4*>(&wl[dst]) =
            *reinterpret_cast<const int4*>(whh + (long)grow * NH + cin * 8);
    }
    // zero A-tile pad rows 8..15 (stay zero forever)
#pragma unroll
    for (int j = 0; j < 2; ++j) {
        int c = tid + 256 * j;
        int lr = 8 + (c >> 6), cin = c & 63;
        int4 z; z.x = z.y = z.z = z.w = 0;
        *reinterpret_cast<int4*>(&hl[lr * NH + cin * 8]) = z;
    }
    // zero initial h (buffer 0) for this WG's slice
    if (tid < 16) {
        i32x4 z = (i32x4){0, 0, 0, 0};
        int bb = tid >> 1, seg = tid & 1;
        gstore16_cc(hf16 + (g * 8 + bb) * NH + e0 + seg * 8, z);
    }
    float hp = 0.f, hrp = 0.f;                 // register-resident h / relu(h)
    __syncthreads();
    flag_barrier(gslots, 32, memb, 1, tid);

    const float bgate = (wv < 3) ? bhh[wv * NH + e0 + (lane & 15)] : 0.f;
    const int b = tid >> 4, e = tid & 15;
    const long rb0 = (long)(g * 8 + b) * NT;

    float xr = 0.f, xz = 0.f, xn = 0.f, nxr = 0.f, nxz = 0.f, nxn = 0.f;
    if (tid < 128) {                           // gx for t=0 (stride 1536)
        long gb = rb0 * 1536 + e0 + e;
        xr = (float)gx[gb]; xz = (float)gx[gb + NH]; xn = (float)gx[gb + 2 * NH];
    }

    for (int t = 0; t < NT; ++t) {
        // deferred hrelu store for t-1 (drains with the h loads below)
        if (tid < 128 && t > 0)
            hrelu[(rb0 + t - 1) * NH + e0 + e] = (half_t)hrp;

        const half_t* hsrc = hf16 + (t & 1) * (NB * NH);
        i32x4 sv[2];
#pragma unroll
        for (int j = 0; j < 2; ++j) {
            int c = tid + 256 * j;             // 512 chunks
            int lr = c >> 6, cin = c & 63;
            gload16_cc(sv[j], hsrc + (g * 8 + lr) * NH + cin * 8);
        }
        asm volatile("s_waitcnt vmcnt(0)" ::: "memory");
#pragma unroll
        for (int j = 0; j < 2; ++j) {
            int c = tid + 256 * j;
            int lr = c >> 6, cin = c & 63;
            *reinterpret_cast<i32x4*>(&hl[lr * NH + ((cin ^ (lr & 7)) << 3)]) = sv[j];
        }
        __syncthreads();

        // prefetch next step's gx (hidden under MFMA + barrier)
        if (tid < 128 && t + 1 < NT) {
            long gb = (rb0 + t + 1) * 1536 + e0 + e;
            nxr = (float)gx[gb]; nxz = (float)gx[gb + NH]; nxn = (float)gx[gb + 2 * NH];
        }

        if (wv < 3) {                          // wave wv computes gate wv
            f32x4 a0 = (f32x4){bgate, bgate, bgate, bgate};
            f32x4 a1 = (f32x4){0.f, 0.f, 0.f, 0.f};
#pragma unroll
            for (int ks = 0; ks < 16; ks += 2) {
                int ar = lane & 15;
                int br = wv * 16 + (lane & 15);
                int ao0 = ar * NH + ((ks * 32 + 8 * (lane >> 4)) ^ ((ar & 7) << 3));
                int bo0 = br * NH + ((ks * 32 + 8 * (lane >> 4)) ^ ((br & 7) << 3));
                int ao1 = ar * NH + (((ks + 1) * 32 + 8 * (lane >> 4)) ^ ((ar & 7) << 3));
                int bo1 = br * NH + (((ks + 1) * 32 + 8 * (lane >> 4)) ^ ((br & 7) << 3));
                a0 = MFMA16(*reinterpret_cast<const half8*>(&hl[ao0]),
                            *reinterpret_cast<const half8*>(&wl[bo0]), a0, 0, 0, 0);
                a1 = MFMA16(*reinterpret_cast<const half8*>(&hl[ao1]),
                            *reinterpret_cast<const half8*>(&wl[bo1]), a1, 0, 0, 0);
            }
            f32x4 acc = a0 + a1;
            if (lane < 32) {
#pragma unroll
                for (int i = 0; i < 4; ++i)
                    xch[wv][4 * (lane >> 4) + i][lane & 15] = acc[i];
            }
        }
        __syncthreads();

        if (tid < 128) {                       // gate combine, one thread per (b,e)
            float r = 1.f / (1.f + __expf(-(xr + xch[0][b][e])));
            float z = 1.f / (1.f + __expf(-(xz + xch[1][b][e])));
            float n = tanhf(xn + r * xch[2][b][e]);
            float hn = (1.f - z) * n + z * hp;
            hp = hn;
            hrp = fmaxf(hn, 0.f);
            hst[b][e] = (half_t)hn;
        }
        __syncthreads();

        if (t + 1 < NT) {
            if (tid < 16) {
                int bb = tid >> 1, seg = tid & 1;
                i32x4 v = *reinterpret_cast<const i32x4*>(&hst[bb][seg * 8]);
                gstore16_cc(hf16 + ((t + 1) & 1) * (NB * NH) + (g * 8 + bb) * NH + e0 + seg * 8, v);
            }
            flag_barrier(gslots, 32, memb, t + 2, tid);
        }
        xr = nxr; xz = nxz; xn = nxn;
    }
    // final hrelu store (t = NT-1)
    if (tid < 128)
        hrelu[(rb0 + NT - 1) * NH + e0 + e] = (half_t)hrp;
}

// ---------------- Phase 2: layer-2 recurrence (persistent) ----------------
// 4 groups x 64 WGs; group g owns batches [16g,16g+16). WG owns 16 out-elems.
// out store for step t-1 deferred to the top of step t (drains with h loads).
__global__ __launch_bounds__(256, 1) void k_phase2(const half_t* __restrict__ whh,
                                                   const float* __restrict__ bhh,
                                                   const half_t* __restrict__ gx,
                                                   float* __restrict__ out,
                                                   half_t* __restrict__ hf16,
                                                   unsigned* __restrict__ slots) {
    __shared__ half_t wl[48 * NI] __attribute__((aligned(16)));   // 96KB
    __shared__ half_t hl[16 * NI] __attribute__((aligned(16)));   // 32KB
    __shared__ float xch2[3][16][16];
    __shared__ half_t hst[16][16] __attribute__((aligned(16)));

    const int tid = threadIdx.x, lane = tid & 63, wv = tid >> 6;
    const int xcd = blockIdx.x & 7;
    const int g = xcd >> 1;
    const int memb = ((blockIdx.x >> 3) << 1) | (xcd & 1);  // 0..63
    const int e0 = memb * 16;
    unsigned* gslots = slots + g * 64;

#pragma unroll
    for (int j = 0; j < 24; ++j) {
        int c = tid + 256 * j;                 // 6144 chunks
        int lr = c >> 7, cin = c & 127;
        int grow = (lr >> 4) * NI + e0 + (lr & 15);
        int dst = lr * NI + ((cin ^ (lr & 7)) << 3);
        *reinterpret_cast<int4*>(&wl[dst]) =
            *reinterpret_cast<const int4*>(whh + (long)grow * NI + cin * 8);
    }
    if (tid < 32) {
        i32x4 z = (i32x4){0, 0, 0, 0};
        int bb = tid >> 1, seg = tid & 1;
        gstore16_cc(hf16 + (g * 16 + bb) * NI + e0 + seg * 8, z);
    }
    float hp = 0.f;
    __syncthreads();
    flag_barrier(gslots, 64, memb, 1, tid);

    const float bgate = (wv < 3) ? bhh[wv * NI + e0 + (lane & 15)] : 0.f;
    const int b = tid >> 4, e = tid & 15;
    const long rb0 = (long)(g * 16 + b) * NT;

    float xr, xz, xn, nxr = 0.f, nxz = 0.f, nxn = 0.f;
    {
        long gb = rb0 * 3072 + e0 + e;
        xr = (float)gx[gb]; xz = (float)gx[gb + NI]; xn = (float)gx[gb + 2 * NI];
    }

    for (int t = 0; t < NT; ++t) {
        // deferred out store for t-1 (drains with the h loads below)
        if (t > 0)
            out[(rb0 + t - 1) * NI + e0 + e] = hp;

        const half_t* hsrc = hf16 + (t & 1) * (NB * NI);
        i32x4 sv[8];
#pragma unroll
        for (int j = 0; j < 8; ++j) {
            int c = tid + 256 * j;             // 2048 chunks
            int lr = c >> 7, cin = c & 127;
            gload16_cc(sv[j], hsrc + (g * 16 + lr) * NI + cin * 8);
        }
        asm volatile("s_waitcnt vmcnt(0)" ::: "memory");
#pragma unroll
        for (int j = 0; j < 8; ++j) {
            int c = tid + 256 * j;
            int lr = c >> 7, cin = c & 127;
            *reinterpret_cast<i32x4*>(&hl[lr * NI + ((cin ^ (lr & 7)) << 3)]) = sv[j];
        }
        __syncthreads();

        if (t + 1 < NT) {                      // prefetch next gx
            long gb = (rb0 + t + 1) * 3072 + e0 + e;
            nxr = (float)gx[gb]; nxz = (float)gx[gb + NI]; nxn = (float)gx[gb + 2 * NI];
        }

        if (wv < 3) {
            f32x4 a0 = (f32x4){bgate, bgate, bgate, bgate};
            f32x4 a1 = (f32x4){0.f, 0.f, 0.f, 0.f};
#pragma unroll
            for (int ks = 0; ks < 32; ks += 2) {
                int ar = lane & 15;
                int br = wv * 16 + (lane & 15);
                int ao0 = ar * NI + ((ks * 32 + 8 * (lane >> 4)) ^ ((ar & 7) << 3));
                int bo0 = br * NI + ((ks * 32 + 8 * (lane >> 4)) ^ ((br & 7) << 3));
                int ao1 = ar * NI + (((ks + 1) * 32 + 8 * (lane >> 4)) ^ ((ar & 7) << 3));
                int bo1 = br * NI + (((ks + 1) * 32 + 8 * (lane >> 4)) ^ ((br & 7) << 3));
                a0 = MFMA16(*reinterpret_cast<const half8*>(&hl[ao0]),
                            *reinterpret_cast<const half8*>(&wl[bo0]), a0, 0, 0, 0);
                a1 = MFMA16(*reinterpret_cast<const half8*>(&hl[ao1]),
                            *reinterpret_cast<const half8*>(&wl[bo1]), a1, 0, 0, 0);
            }
            f32x4 acc = a0 + a1;
#pragma unroll
            for (int i = 0; i < 4; ++i)
                xch2[wv][4 * (lane >> 4) + i][lane & 15] = acc[i];
        }
        __syncthreads();

        {
            float r = 1.f / (1.f + __expf(-(xr + xch2[0][b][e])));
            float z = 1.f / (1.f + __expf(-(xz + xch2[1][b][e])));
            float n = tanhf(xn + r * xch2[2][b][e]);
            float hn = (1.f - z) * n + z * hp;
            hp = hn;
            hst[b][e] = (half_t)hn;
        }
        __syncthreads();

        if (t + 1 < NT) {
            if (tid < 32) {
                int bb = tid >> 1, seg = tid & 1;
                i32x4 v = *reinterpret_cast<const i32x4*>(&hst[bb][seg * 8]);
                gstore16_cc(hf16 + ((t + 1) & 1) * (NB * NI) + (g * 16 + bb) * NI + e0 + seg * 8, v);
            }
            flag_barrier(gslots, 64, memb, t + 2, tid);
        }
        xr = nxr; xz = nxz; xn = nxn;
    }
    // final out store (t = NT-1)
    out[(rb0 + NT - 1) * NI + e0 + e] = hp;
}

// ---------------- launcher ----------------
extern "C" void kernel_launch(void* const* d_in, const int* in_sizes, int n_in,
                              void* d_out, int out_size, void* d_ws, size_t ws_size,
                              hipStream_t stream) {
    const float* x     = (const float*)d_in[0];
    const float* w_ih1 = (const float*)d_in[1];
    const float* w_hh1 = (const float*)d_in[2];
    const float* b_ih1 = (const float*)d_in[3];
    const float* b_hh1 = (const float*)d_in[4];
    const float* w_ih2 = (const float*)d_in[5];
    const float* w_hh2 = (const float*)d_in[6];
    const float* b_ih2 = (const float*)d_in[7];
    const float* b_hh2 = (const float*)d_in[8];

    char* ws = (char*)d_ws;
    // layout (ends at 144MB; ws >= 151MB proven in rounds 1/3):
    unsigned* slots1 = (unsigned*)ws;                  // [0, 2K)
    unsigned* slots2 = (unsigned*)(ws + 2048);         // [2K, 3K)
    half_t* h1f16  = (half_t*)(ws + 4096);             // 2 x 64x512 fp16 ping-pong
    half_t* h2f16  = (half_t*)(ws + 135168);           // 2 x 64x1024 fp16
    half_t* whh1h  = (half_t*)(ws + 4194304);          // 1536x512
    half_t* wih2h  = (half_t*)(ws + 5767168);          // 3072x512
    half_t* whh2h  = (half_t*)(ws + 8912896);          // 3072x1024 -> ends 14.9MB
    half_t* hrelu  = (half_t*)(ws + 16777216);         // [16,32)MB: [B][T][512] f16
    half_t* gxU    = (half_t*)(ws + 50331648);         // [48,144)MB: gx1 then gx2
    float*  out    = (float*)d_out;

    hipMemsetAsync(ws, 0, 4096, stream);               // barrier slots = 0

    k_cvt<<<768,  256, 0, stream>>>(w_hh1, whh1h, 196608);
    k_cvt<<<1536, 256, 0, stream>>>(w_ih2, wih2h, 393216);
    k_cvt<<<3072, 256, 0, stream>>>(w_hh2, whh2h, 786432);

    // gx1 = x @ w_ih1^T + b_ih1   [16384 x 1536], K=1024 (A and B fp32, staged-cvt)
    k_gemm<1024, true, true><<<dim3(12, 128), 256, 0, stream>>>(x, w_ih1, b_ih1, gxU, 1536, 1536);
    // layer-1 recurrence -> hrelu
    k_phase1<<<256, 256, 0, stream>>>(whh1h, b_hh1, gxU, hrelu, h1f16, slots1);
    // gx2 = relu(h1) @ w_ih2^T + b_ih2   [16384 x 3072], K=512 (overwrites gx1, now dead)
    k_gemm<512, false, false><<<dim3(24, 128), 256, 0, stream>>>(hrelu, wih2h, b_ih2, gxU, 3072, 3072);
    // layer-2 recurrence -> out (fp32)
    k_phase2<<<256, 256, 0, stream>>>(whh2h, b_hh2, gxU, out, h2f16, slots2);
}